// Round 4
// baseline (172.811 us; speedup 1.0000x reference)
//
#include <hip/hip_runtime.h>

// Committee vote histogram:
//   logits[m,b,c] = x[b,:] . W[m,:,c] + bias[m,c]
//   votes[m,b]    = argmax_c logits
//   out[b,c]      = #{ m : votes[m,b] == c }   (float32)
//
// B=65536, D=512, M=16, C=10.
// Block = 1024 threads (16 waves), one model per wave (W via wave-uniform
// s_loads), 128 rows per block = TWO 64-row groups per wave so each W dword
// feeds 2 FMAs (doubles the VALU duty cycle against s_load latency — the
// round-3 bottleneck). KCHUNK=32 keeps the unrolled chunk body at the proven
// 640-FMA size (round-2's 1280-FMA body spilled). Double-buffered LDS with
// register prefetch one chunk ahead.

#define DDIM    512
#define NCLS    10
#define ROWS    128                 // rows per block (2 groups of 64)
#define KCHUNK  32
#define NCHUNK  (DDIM / KCHUNK)     // 16
#define ROWP    129                 // float4 row stride (odd)

__global__ __launch_bounds__(1024, 2)
void committee_kernel(const float* __restrict__ x,
                      const float* __restrict__ W,
                      const float* __restrict__ bias,
                      float* __restrict__ out)
{
    // xs[buf][kq][row]: x[row][ch*32 + 4*kq .. +3]
    __shared__ float4 xs[2][8][ROWP];
    __shared__ int ihist[ROWS * NCLS];

    const int tid  = threadIdx.x;
    const int row0 = blockIdx.x * ROWS;

    for (int i = tid; i < ROWS * NCLS; i += 1024) ihist[i] = 0;

    const int m    = __builtin_amdgcn_readfirstlane(tid >> 6);  // wave = model
    const int lane = tid & 63;

    const float* wp = W + (size_t)m * DDIM * NCLS;

    float acc0[NCLS];   // rows row0 + lane
    float acc1[NCLS];   // rows row0 + 64 + lane
#pragma unroll
    for (int c = 0; c < NCLS; ++c) {
        const float bv = bias[m * NCLS + c];
        acc0[c] = bv;
        acc1[c] = bv;
    }

    // staging: thread t loads x[row0 + t/8][ch*32 + 4*(t%8) .. +3]
    const int srow = tid >> 3;   // 0..127
    const int skq  = tid & 7;    // 0..7
    const float* gsrc = x + (size_t)(row0 + srow) * DDIM + (skq << 2);

    // prologue: stage chunk 0 directly, issue load for chunk 1
    float4 pa = *reinterpret_cast<const float4*>(gsrc);
    xs[0][skq][srow] = pa;
    pa = *reinterpret_cast<const float4*>(gsrc + KCHUNK);

    for (int ch = 0; ch < NCHUNK; ++ch) {
        __syncthreads();           // prev readers of buf[cur^1] done;
        const int cur = ch & 1;    // buf[cur] writes visible

        if (ch + 1 < NCHUNK) {
            // write prefetched chunk ch+1 (its load had a full compute phase
            // to land), then issue the load for ch+2
            xs[cur ^ 1][skq][srow] = pa;
            if (ch + 2 < NCHUNK) {
                pa = *reinterpret_cast<const float4*>(
                    gsrc + (size_t)(ch + 2) * KCHUNK);
            }
        }

#pragma unroll
        for (int kq = 0; kq < 8; ++kq) {
            const float4 x0 = xs[cur][kq][lane];
            const float4 x1 = xs[cur][kq][64 + lane];
            const float xa[4] = {x0.x, x0.y, x0.z, x0.w};
            const float xb[4] = {x1.x, x1.y, x1.z, x1.w};
            // W chunk for this wave's model: wave-uniform -> s_load
            const float* wk = wp + (size_t)(ch * KCHUNK + (kq << 2)) * NCLS;
#pragma unroll
            for (int j = 0; j < 4; ++j) {
                const float a0 = xa[j];
                const float a1 = xb[j];
#pragma unroll
                for (int c = 0; c < NCLS; ++c) {
                    const float w = wk[j * NCLS + c];
                    acc0[c] = fmaf(a0, w, acc0[c]);
                    acc1[c] = fmaf(a1, w, acc1[c]);
                }
            }
        }
    }

    // argmax, first-occurrence-of-max semantics (strict >)
    {
        int best = 0;
        float bv = acc0[0];
#pragma unroll
        for (int c = 1; c < NCLS; ++c) {
            if (acc0[c] > bv) { bv = acc0[c]; best = c; }
        }
        atomicAdd(&ihist[lane * NCLS + best], 1);
    }
    {
        int best = 0;
        float bv = acc1[0];
#pragma unroll
        for (int c = 1; c < NCLS; ++c) {
            if (acc1[c] > bv) { bv = acc1[c]; best = c; }
        }
        atomicAdd(&ihist[(64 + lane) * NCLS + best], 1);
    }
    __syncthreads();

    for (int i = tid; i < ROWS * NCLS; i += 1024) {
        out[(size_t)row0 * NCLS + i] = (float)ihist[i];
    }
}

extern "C" void kernel_launch(void* const* d_in, const int* in_sizes, int n_in,
                              void* d_out, int out_size, void* d_ws, size_t ws_size,
                              hipStream_t stream) {
    const float* x  = (const float*)d_in[0];   // [65536, 512]
    const float* W  = (const float*)d_in[1];   // [16, 512, 10]
    const float* b  = (const float*)d_in[2];   // [16, 10]
    float* out      = (float*)d_out;           // [65536, 10]

    const int nblocks = 65536 / ROWS;          // 512
    committee_kernel<<<nblocks, 1024, 0, stream>>>(x, W, b, out);
}